// Round 5
// baseline (795.708 us; speedup 1.0000x reference)
//
#include <hip/hip_runtime.h>
#include <hip/hip_bf16.h>

constexpr int IN_ = 256, H_ = 128, HN_ = 4;
constexpr int S_ = 5, B_ = 1024, M_ = 16, D_ = 512;

typedef __attribute__((ext_vector_type(8))) short bf16x8;
typedef __attribute__((ext_vector_type(4))) float f32x4;
typedef __attribute__((ext_vector_type(4))) short s16x4;

__device__ __forceinline__ float lrelu(float z) { return z >= 0.f ? z : 0.2f * z; }
__device__ __forceinline__ short f2b(float f) {            // RNE f32->bf16
    unsigned u = __float_as_uint(f);
    u += 0x7FFF + ((u >> 16) & 1);
    return (short)(u >> 16);
}
__device__ __forceinline__ float b2f(short s) {
    return __uint_as_float(((unsigned)(unsigned short)s) << 16);
}

// ---------------------------------------------------------------------------
// GEMM building blocks. All per-wave 16xK @ Kx128 via mfma_f32_16x16x32_bf16.
// A-frag: row = lane&15, k = (lane>>4)*8 + j (+32*kk).
// B-frag: W[128][K] row-major -> B[k][n]=W[n][k], contiguous 16B per lane.
// C/D:    col = lane&15 (+16*cb), row = (lane>>4)*4 + i.
// LDS tiles are XOR-swizzled: element (r,c) at r*128 + (c ^ ((r&7)<<3)).
// ---------------------------------------------------------------------------

// G1 flavor: A-frags already in registers (af[8] covers K=256).
template<int ACT, bool TG>
__device__ __forceinline__ void gemm_regA(
    const bf16x8* af, const short* __restrict__ W, const float* __restrict__ bias,
    short* C_lds, short* __restrict__ C_glob, int lane)
{
    f32x4 acc[8];
#pragma unroll
    for (int i = 0; i < 8; ++i) acc[i] = (f32x4){0.f, 0.f, 0.f, 0.f};
    const int m16 = lane & 15, kg = (lane >> 4) * 8;
#pragma unroll
    for (int kk8 = 0; kk8 < 8; ++kk8) {
        const short* Wb = W + (size_t)m16 * 256 + 32 * kk8 + kg;
#pragma unroll
        for (int cb = 0; cb < 8; ++cb) {
            bf16x8 bf = *(const bf16x8*)(Wb + (size_t)cb * 16 * 256);
            acc[cb] = __builtin_amdgcn_mfma_f32_16x16x32_bf16(af[kk8], bf, acc[cb], 0, 0, 0);
        }
    }
    const int r0 = (lane >> 4) * 4;
#pragma unroll
    for (int cb = 0; cb < 8; ++cb) {
        const int col = cb * 16 + m16;
        const float bv = bias[col];
#pragma unroll
        for (int i = 0; i < 4; ++i) {
            const int r = r0 + i;
            float v = acc[cb][i] + bv;
            if (ACT) v = lrelu(v);
            const short bs = f2b(v);
            C_lds[r * H_ + (col ^ ((r & 7) << 3))] = bs;
            if (TG) C_glob[(size_t)r * H_ + col] = bs;
        }
    }
}

// A from LDS (swizzled), C to LDS and/or global.
template<int K, int ACT, bool TLDS, bool TGLB>
__device__ __forceinline__ void gemm_ldsA(
    const short* A, const short* __restrict__ W, const float* __restrict__ bias,
    short* C_lds, short* __restrict__ C_glob, int lane)
{
    f32x4 acc[8];
#pragma unroll
    for (int i = 0; i < 8; ++i) acc[i] = (f32x4){0.f, 0.f, 0.f, 0.f};
    const int m16 = lane & 15;
    const int kg  = (lane >> 4) * 8;
    const short* Ab = A + m16 * K;
    const int aswz = (m16 & 7) << 3;
#pragma unroll
    for (int kk = 0; kk < K; kk += 32) {
        bf16x8 afr = *(const bf16x8*)(Ab + ((kk + kg) ^ aswz));
        const short* Wb = W + (size_t)m16 * K + kk + kg;
#pragma unroll
        for (int cb = 0; cb < 8; ++cb) {
            bf16x8 bf = *(const bf16x8*)(Wb + (size_t)cb * 16 * K);
            acc[cb] = __builtin_amdgcn_mfma_f32_16x16x32_bf16(afr, bf, acc[cb], 0, 0, 0);
        }
    }
    const int r0 = (lane >> 4) * 4;
#pragma unroll
    for (int cb = 0; cb < 8; ++cb) {
        const int col = cb * 16 + m16;
        const float bv = bias ? bias[col] : 0.f;
#pragma unroll
        for (int i = 0; i < 4; ++i) {
            const int r = r0 + i;
            float v = acc[cb][i] + bv;
            if (ACT) v = lrelu(v);
            const short bs = f2b(v);
            if (TLDS) C_lds[r * H_ + (col ^ ((r & 7) << 3))] = bs;
            if (TGLB) C_glob[(size_t)r * H_ + col] = bs;
        }
    }
}

// A from LDS, result stays in registers (bias+act applied).
template<int K, int ACT>
__device__ __forceinline__ void gemm_ldsA_reg(
    const short* A, const short* __restrict__ W, const float* __restrict__ bias,
    f32x4* acc, int lane)
{
#pragma unroll
    for (int i = 0; i < 8; ++i) acc[i] = (f32x4){0.f, 0.f, 0.f, 0.f};
    const int m16 = lane & 15;
    const int kg  = (lane >> 4) * 8;
    const short* Ab = A + m16 * K;
    const int aswz = (m16 & 7) << 3;
#pragma unroll
    for (int kk = 0; kk < K; kk += 32) {
        bf16x8 afr = *(const bf16x8*)(Ab + ((kk + kg) ^ aswz));
        const short* Wb = W + (size_t)m16 * K + kk + kg;
#pragma unroll
        for (int cb = 0; cb < 8; ++cb) {
            bf16x8 bf = *(const bf16x8*)(Wb + (size_t)cb * 16 * K);
            acc[cb] = __builtin_amdgcn_mfma_f32_16x16x32_bf16(afr, bf, acc[cb], 0, 0, 0);
        }
    }
#pragma unroll
    for (int cb = 0; cb < 8; ++cb) {
        const float bv = bias[cb * 16 + m16];
#pragma unroll
        for (int i = 0; i < 4; ++i) {
            float v = acc[cb][i] + bv;
            if (ACT) v = lrelu(v);
            acc[cb][i] = v;
        }
    }
}

// Load A-frags (K=256) for 16 gathered rows straight from global f32.
__device__ __forceinline__ void load_afrags(
    const float* __restrict__ x, int g, int lane, bf16x8* af)
{
    const float* xr = x + (size_t)g * IN_ + (lane >> 4) * 8;
#pragma unroll
    for (int c = 0; c < 8; ++c) {
        float4 u = *(const float4*)(xr + 32 * c);
        float4 v = *(const float4*)(xr + 32 * c + 4);
        bf16x8 a;
        a[0] = f2b(u.x); a[1] = f2b(u.y); a[2] = f2b(u.z); a[3] = f2b(u.w);
        a[4] = f2b(v.x); a[5] = f2b(v.y); a[6] = f2b(v.z); a[7] = f2b(v.w);
        af[c] = a;
    }
}

// ---- f32->bf16 weight conversion (7 tensors) ----
__global__ __launch_bounds__(256) void k_convert(
    const float* f0, const float* f1, const float* f2, const float* f3,
    const float* f4, const float* f5, const float* f6,
    short* g0, short* g1, short* g2, short* g3, short* g4, short* g5, short* g6)
{
    const float* s; short* d; int n;
    switch (blockIdx.y) {
        case 0: s = f0; d = g0; n = 655360; break;
        case 1: s = f1; d = g1; n = 327680; break;
        case 2: s = f2; d = g2; n = 327680; break;
        case 3: s = f3; d = g3; n = 327680; break;
        case 4: s = f4; d = g4; n = 131072; break;
        case 5: s = f5; d = g5; n = 131072; break;
        default: s = f6; d = g6; n = 131072; break;
    }
    int i = (blockIdx.x * 256 + threadIdx.x) * 4;
    if (i >= n) return;
    float4 v = *(const float4*)(s + i);
    s16x4 p; p.x = f2b(v.x); p.y = f2b(v.y); p.z = f2b(v.z); p.w = f2b(v.w);
    *(s16x4*)(d + i) = p;
}

// ---- K1: target chain (fc->q->a2->aW) -> x_shb, wh2b. Wave-private, no barriers. ----
__global__ __launch_bounds__(256, 4) void k_target(
    const float* __restrict__ x, const int* __restrict__ tgt,
    const short* __restrict__ wb_fc, const float* __restrict__ fc_b,
    const short* __restrict__ wb_q,  const float* __restrict__ q_b,
    const short* __restrict__ wb_a2, const float* __restrict__ a2_b,
    const short* __restrict__ wb_aW,
    short* __restrict__ x_shb, short* __restrict__ wh2b)
{
    const int t = threadIdx.x, lane = t & 63, w = t >> 6;
    const int bt = blockIdx.x, h = blockIdx.y, s = blockIdx.z;
    const int km = (s < 2) ? 0 : 1;
    const int sh = s * HN_ + h, kh = km * HN_ + h;
    const int b0w = bt * 64 + w * 16;

    __shared__ __align__(16) short BUF0[4 * 2048];   // 16 KB: Y -> Q -> H2 (chained reuse)
    short* buf0 = BUF0 + w * 2048;

    bf16x8 af[8];
    load_afrags(x, tgt[b0w + (lane & 15)], lane, af);

    gemm_regA<1, true>(af, wb_fc + (size_t)sh * H_ * IN_, fc_b + sh * H_,
                       buf0, x_shb + ((size_t)sh * B_ + b0w) * H_, lane);
    gemm_ldsA<H_, 0, true, false>(buf0, wb_q + (size_t)sh * H_ * H_, q_b + sh * H_,
                                  buf0, nullptr, lane);
    gemm_ldsA<H_, 1, true, false>(buf0, wb_a2 + (size_t)kh * H_ * H_, a2_b + kh * H_,
                                  buf0, nullptr, lane);
    gemm_ldsA<H_, 0, false, true>(buf0, wb_aW + (size_t)kh * H_ * H_, nullptr,
                                  nullptr, wh2b + ((size_t)sh * B_ + b0w) * H_, lane);
}

// ---- K2: neighbor pipeline. Wave-private buffers, H1 in registers, no barriers. ----
__global__ __launch_bounds__(256, 4) void k_neighbor(
    const float* __restrict__ x, const int* __restrict__ nbr,
    const short* __restrict__ wb_fc, const float* __restrict__ fc_b,
    const short* __restrict__ wb_k,  const float* __restrict__ k_b,
    const short* __restrict__ wb_v,  const float* __restrict__ v_b,
    const short* __restrict__ wb_a1, const float* __restrict__ a1_b,
    const short* __restrict__ x_shb, const short* __restrict__ wh2b,
    float* __restrict__ out_sbd)
{
    const int t = threadIdx.x, lane = t & 63, w = t >> 6;
    const int bt = blockIdx.x, h = blockIdx.y, s = blockIdx.z;
    const int km = (s < 2) ? 0 : 1;
    const int sh = s * HN_ + h, kh = km * HN_ + h;
    const int b = bt * 4 + w;
    const int m16 = lane & 15;

    __shared__ __align__(16) short BUF0[4 * 2048];   // 8 KB: Y -> Kh
    __shared__ __align__(16) short BUFV[4 * 2048];   // 8 KB: Vh
    short* buf0 = BUF0 + w * 2048;
    short* bufV = BUFV + w * 2048;

    bf16x8 af[8];
    load_afrags(x, nbr[((size_t)s * B_ + b) * M_ + m16], lane, af);

    // G1: Y = lrelu(fc(ny)) -> buf0
    gemm_regA<1, false>(af, wb_fc + (size_t)sh * H_ * IN_, fc_b + sh * H_,
                        buf0, nullptr, lane);
    // G3: Vh = v(Y) -> bufV   (before G2 overwrites Y)
    gemm_ldsA<H_, 0, true, false>(buf0, wb_v + (size_t)sh * H_ * H_, v_b + sh * H_,
                                  bufV, nullptr, lane);
    // G2: Kh = k(Y) -> buf0 (over Y; same-wave DS ordering makes this safe)
    gemm_ldsA<H_, 0, true, false>(buf0, wb_k + (size_t)sh * H_ * H_, k_b + sh * H_,
                                  buf0, nullptr, lane);
    // G4: H1 = lrelu(a1(Kh)) -> registers
    f32x4 h1[8];
    gemm_ldsA_reg<H_, 1>(buf0, wb_a1 + (size_t)kh * H_ * H_, a1_b + kh * H_, h1, lane);

    // scores: att[m] = h1[m] . wh2[b]; lane holds cols m16+16cb, rows 4*(l>>4)+i
    const short* wrow = wh2b + ((size_t)sh * B_ + b) * H_;
    float p4[4] = {0.f, 0.f, 0.f, 0.f};
#pragma unroll
    for (int cb = 0; cb < 8; ++cb) {
        const float wv = b2f(wrow[cb * 16 + m16]);
#pragma unroll
        for (int i = 0; i < 4; ++i) p4[i] += h1[cb][i] * wv;
    }
#pragma unroll
    for (int i = 0; i < 4; ++i) {
        p4[i] += __shfl_xor(p4[i], 1);
        p4[i] += __shfl_xor(p4[i], 2);
        p4[i] += __shfl_xor(p4[i], 4);
        p4[i] += __shfl_xor(p4[i], 8);
    }
    float e[16];
    float mx = -1e30f;
#pragma unroll
    for (int mm = 0; mm < 16; ++mm) {
        e[mm] = __shfl(p4[mm & 3], (mm >> 2) << 4);
        mx = fmaxf(mx, e[mm]);
    }
    float ssum = 0.f;
#pragma unroll
    for (int mm = 0; mm < 16; ++mm) { e[mm] = expf(e[mm] - mx); ssum += e[mm]; }
    const float inv = 1.f / ssum;

    // out = (x_sh + sum_m lrelu(vh*e)) * 0.5
    const short* xrow = x_shb + ((size_t)sh * B_ + b) * H_;
    float* orow = out_sbd + ((size_t)s * B_ + b) * D_ + h * H_;
#pragma unroll
    for (int rep = 0; rep < 2; ++rep) {
        const int d = rep * 64 + lane;
        float hacc = 0.f;
#pragma unroll
        for (int mm = 0; mm < 16; ++mm) {
            const float vv = b2f(bufV[mm * H_ + (d ^ ((mm & 7) << 3))]);
            hacc += lrelu(vv * (e[mm] * inv));
        }
        orow[d] = (b2f(xrow[d]) + hacc) * 0.5f;
    }
}

// ---- K3: fused inner + between semantic attention (f32, shuffle reductions) ----
__global__ __launch_bounds__(256) void k_semantic(
    const float* __restrict__ out_sbd,
    const float* __restrict__ ip1w, const float* __restrict__ ip1b,
    const float* __restrict__ ip2w,
    const float* __restrict__ bp1w, const float* __restrict__ bp1b,
    const float* __restrict__ bp2w,
    float* __restrict__ out)
{
    const int b = blockIdx.x, t = threadIdx.x;
    __shared__ float zs[S_ * D_];
    __shared__ float mps[2 * D_];
    __shared__ float red[128];
    __shared__ float svals[3];
    __shared__ float beta_s[3];

    for (int idx = t; idx < S_ * D_ / 4; idx += 256) {
        int sidx = idx >> 7, c = idx & 127;
        ((float4*)zs)[idx] = ((const float4*)(out_sbd + ((size_t)sidx * B_ + b) * D_))[c];
    }
    __syncthreads();

    for (int ki = 0; ki < 2; ++ki) {
        const int s0 = (ki == 0) ? 0 : 2;
        const int P = (ki == 0) ? 2 : 3;
        for (int p = 0; p < P; ++p) {
            if (t < H_) {
                const float* wrow = ip1w + ((size_t)ki * H_ + t) * D_;
                const float* zrow = zs + (s0 + p) * D_;
                float acc = 0.f;
                for (int d = 0; d < D_; d += 4) {
                    float4 w4 = *(const float4*)(wrow + d);
                    float4 z4 = *(const float4*)(zrow + d);
                    acc += w4.x * z4.x + w4.y * z4.y + w4.z * z4.z + w4.w * z4.w;
                }
                red[t] = tanhf(acc + ip1b[ki * H_ + t]) * ip2w[ki * H_ + t];
            }
            __syncthreads();
            if (t < 64) {
                float sv = red[t] + red[t + 64];
#pragma unroll
                for (int o = 32; o; o >>= 1) sv += __shfl_down(sv, o);
                if (t == 0) svals[p] = sv;
            }
            __syncthreads();
        }
        if (t == 0) {
            float mx = svals[0];
            for (int p = 1; p < P; ++p) mx = fmaxf(mx, svals[p]);
            float sum = 0.f;
            for (int p = 0; p < P; ++p) { float e = expf(svals[p] - mx); beta_s[p] = e; sum += e; }
            for (int p = 0; p < P; ++p) beta_s[p] /= sum;
        }
        __syncthreads();
        for (int d = t; d < D_; d += 256) {
            float acc = 0.f;
            for (int p = 0; p < P; ++p) acc += beta_s[p] * zs[(s0 + p) * D_ + d];
            mps[ki * D_ + d] = acc;
        }
        __syncthreads();
    }

    for (int p = 0; p < 2; ++p) {
        if (t < H_) {
            const float* wrow = bp1w + (size_t)t * D_;
            const float* zrow = mps + p * D_;
            float acc = 0.f;
            for (int d = 0; d < D_; d += 4) {
                float4 w4 = *(const float4*)(wrow + d);
                float4 z4 = *(const float4*)(zrow + d);
                acc += w4.x * z4.x + w4.y * z4.y + w4.z * z4.z + w4.w * z4.w;
            }
            red[t] = tanhf(acc + bp1b[t]) * bp2w[t];
        }
        __syncthreads();
        if (t < 64) {
            float sv = red[t] + red[t + 64];
#pragma unroll
            for (int o = 32; o; o >>= 1) sv += __shfl_down(sv, o);
            if (t == 0) svals[p] = sv;
        }
        __syncthreads();
    }
    if (t == 0) {
        float mx = fmaxf(svals[0], svals[1]);
        float e0 = expf(svals[0] - mx), e1 = expf(svals[1] - mx);
        float inv = 1.f / (e0 + e1);
        beta_s[0] = e0 * inv; beta_s[1] = e1 * inv;
    }
    __syncthreads();
    for (int d = t; d < D_; d += 256)
        out[(size_t)b * D_ + d] = beta_s[0] * mps[d] + beta_s[1] * mps[D_ + d];
}

extern "C" void kernel_launch(void* const* d_in, const int* in_sizes, int n_in,
                              void* d_out, int out_size, void* d_ws, size_t ws_size,
                              hipStream_t stream)
{
    const float* x    = (const float*)d_in[0];
    const int*   tgt  = (const int*)d_in[1];
    const int*   nbr  = (const int*)d_in[2];
    const float* fc_w = (const float*)d_in[3];
    const float* fc_b = (const float*)d_in[4];
    const float* q_w  = (const float*)d_in[5];
    const float* q_b  = (const float*)d_in[6];
    const float* k_w  = (const float*)d_in[7];
    const float* k_b  = (const float*)d_in[8];
    const float* v_w  = (const float*)d_in[9];
    const float* v_b  = (const float*)d_in[10];
    const float* attW = (const float*)d_in[11];
    const float* a1w  = (const float*)d_in[12];
    const float* a1b  = (const float*)d_in[13];
    const float* a2w  = (const float*)d_in[14];
    const float* a2b  = (const float*)d_in[15];
    const float* ip1w = (const float*)d_in[16];
    const float* ip1b = (const float*)d_in[17];
    const float* ip2w = (const float*)d_in[18];
    const float* bp1w = (const float*)d_in[19];
    const float* bp1b = (const float*)d_in[20];
    const float* bp2w = (const float*)d_in[21];

    float* out = (float*)d_out;

    // ws layout (shorts unless noted)
    short* wb_fc = (short*)d_ws;               // 655,360  (S,HN,H,IN)
    short* wb_q  = wb_fc + 655360;             // 327,680  (S,HN,H,H)
    short* wb_k  = wb_q + 327680;
    short* wb_v  = wb_k + 327680;
    short* wb_aW = wb_v + 327680;              // 131,072  (K,HN,H,H)
    short* wb_a1 = wb_aW + 131072;
    short* wb_a2 = wb_a1 + 131072;
    short* x_shb = wb_a2 + 131072;             // 2,621,440 (S,HN,B,H)
    short* wh2b  = x_shb + 2621440;            // 2,621,440
    float* out_sbd = (float*)(wh2b + 2621440); // 2,621,440 f32 (S,B,D)

    k_convert<<<dim3(640, 7), 256, 0, stream>>>(
        fc_w, q_w, k_w, v_w, attW, a1w, a2w,
        wb_fc, wb_q, wb_k, wb_v, wb_aW, wb_a1, wb_a2);
    k_target<<<dim3(16, HN_, S_), 256, 0, stream>>>(
        x, tgt, wb_fc, fc_b, wb_q, q_b, wb_a2, a2b, wb_aW, x_shb, wh2b);
    k_neighbor<<<dim3(256, HN_, S_), 256, 0, stream>>>(
        x, nbr, wb_fc, fc_b, wb_k, k_b, wb_v, v_b, wb_a1, a1b, x_shb, wh2b, out_sbd);
    k_semantic<<<dim3(B_), 256, 0, stream>>>(
        out_sbd, ip1w, ip1b, ip2w, bp1w, bp1b, bp2w, out);
}

// Round 7
// 570.512 us; speedup vs baseline: 1.3947x; 1.3947x over previous
//
#include <hip/hip_runtime.h>
#include <hip/hip_bf16.h>

constexpr int IN_ = 256, H_ = 128, HN_ = 4;
constexpr int S_ = 5, B_ = 1024, M_ = 16, D_ = 512;

typedef __attribute__((ext_vector_type(8))) short bf16x8;
typedef __attribute__((ext_vector_type(4))) float f32x4;
typedef __attribute__((ext_vector_type(4))) short s16x4;

__device__ __forceinline__ float lrelu(float z) { return z >= 0.f ? z : 0.2f * z; }
__device__ __forceinline__ short f2b(float f) {            // RNE f32->bf16
    unsigned u = __float_as_uint(f);
    u += 0x7FFF + ((u >> 16) & 1);
    return (short)(u >> 16);
}
__device__ __forceinline__ float b2f(short s) {
    return __uint_as_float(((unsigned)(unsigned short)s) << 16);
}

// ---------------------------------------------------------------------------
// MFMA frag conventions (mfma_f32_16x16x32_bf16):
// A-frag: row = lane&15, k = (lane>>4)*8 + j.  B-frag: B[k][n]=W[n][k] -> 16B/lane.
// C/D: col = lane&15, row = (lane>>4)*4 + i.
// LDS tiles XOR-swizzled: element (r,c) at r*LD + (c ^ ((r&7)<<3)), granule 8 shorts.
// ---------------------------------------------------------------------------

// per-wave 16xK @ Kx128 GEMM, A in LDS (16 rows), full 128 cols. (k_target)
template<int K, int ACT, bool TLDS, bool TGLB>
__device__ __forceinline__ void gemm_ldsA(
    const short* A, const short* __restrict__ W, const float* __restrict__ bias,
    short* C_lds, short* __restrict__ C_glob, int lane)
{
    f32x4 acc[8];
#pragma unroll
    for (int i = 0; i < 8; ++i) acc[i] = (f32x4){0.f, 0.f, 0.f, 0.f};
    const int m16 = lane & 15;
    const int kg  = (lane >> 4) * 8;
    const short* Ab = A + m16 * K;
    const int aswz = (m16 & 7) << 3;
#pragma unroll
    for (int kk = 0; kk < K; kk += 32) {
        bf16x8 afr = *(const bf16x8*)(Ab + ((kk + kg) ^ aswz));
        const short* Wb = W + (size_t)m16 * K + kk + kg;
#pragma unroll
        for (int cb = 0; cb < 8; ++cb) {
            bf16x8 bf = *(const bf16x8*)(Wb + (size_t)cb * 16 * K);
            acc[cb] = __builtin_amdgcn_mfma_f32_16x16x32_bf16(afr, bf, acc[cb], 0, 0, 0);
        }
    }
    const int r0 = (lane >> 4) * 4;
#pragma unroll
    for (int cb = 0; cb < 8; ++cb) {
        const int col = cb * 16 + m16;
        const float bv = bias ? bias[col] : 0.f;
#pragma unroll
        for (int i = 0; i < 4; ++i) {
            const int r = r0 + i;
            float v = acc[cb][i] + bv;
            if (ACT) v = lrelu(v);
            const short bs = f2b(v);
            if (TLDS) C_lds[r * H_ + (col ^ ((r & 7) << 3))] = bs;
            if (TGLB) C_glob[(size_t)r * H_ + col] = bs;
        }
    }
}

// 64-row x 32-col (2 cb) wave GEMM, K=256, A in LDS [64][256] swz. -> C LDS [64][128] swz.
template<int ACT>
__device__ __forceinline__ void tile_gemm256(
    const short* Asrc, const short* __restrict__ W, const float* __restrict__ bias,
    short* Cdst, int lane, int colb)
{
    f32x4 acc[4][2];
#pragma unroll
    for (int a = 0; a < 4; ++a)
#pragma unroll
        for (int b = 0; b < 2; ++b) acc[a][b] = (f32x4){0.f, 0.f, 0.f, 0.f};
    const int m16 = lane & 15, kg = (lane >> 4) * 8;
#pragma unroll
    for (int kk = 0; kk < 8; ++kk) {
        const int k0 = kk * 32 + kg;
        bf16x8 af[4];
#pragma unroll
        for (int rg = 0; rg < 4; ++rg) {
            const int row = rg * 16 + m16;
            af[rg] = *(const bf16x8*)(Asrc + row * 256 + (k0 ^ ((row & 7) << 3)));
        }
#pragma unroll
        for (int cbl = 0; cbl < 2; ++cbl) {
            const int col = colb + cbl * 16 + m16;
            bf16x8 bf = *(const bf16x8*)(W + (size_t)col * 256 + k0);
#pragma unroll
            for (int rg = 0; rg < 4; ++rg)
                acc[rg][cbl] = __builtin_amdgcn_mfma_f32_16x16x32_bf16(af[rg], bf, acc[rg][cbl], 0, 0, 0);
        }
    }
#pragma unroll
    for (int cbl = 0; cbl < 2; ++cbl) {
        const int col = colb + cbl * 16 + m16;
        const float bv = bias[col];
#pragma unroll
        for (int rg = 0; rg < 4; ++rg)
#pragma unroll
            for (int i = 0; i < 4; ++i) {
                const int row = rg * 16 + (lane >> 4) * 4 + i;
                float v = acc[rg][cbl][i] + bv;
                if (ACT) v = lrelu(v);
                Cdst[row * 128 + (col ^ ((row & 7) << 3))] = f2b(v);
            }
    }
}

// 64-row x 32-col wave GEMM, K=128, A in LDS [64][128] swz. MIDBAR inserts a
// block barrier between compute and write (for safe in-place A overwrite).
template<int ACT, bool MIDBAR>
__device__ __forceinline__ void tile_gemm128(
    const short* Asrc, const short* __restrict__ W, const float* __restrict__ bias,
    short* Cdst, int lane, int colb)
{
    f32x4 acc[4][2];
#pragma unroll
    for (int a = 0; a < 4; ++a)
#pragma unroll
        for (int b = 0; b < 2; ++b) acc[a][b] = (f32x4){0.f, 0.f, 0.f, 0.f};
    const int m16 = lane & 15, kg = (lane >> 4) * 8;
#pragma unroll
    for (int kk = 0; kk < 4; ++kk) {
        const int k0 = kk * 32 + kg;
        bf16x8 af[4];
#pragma unroll
        for (int rg = 0; rg < 4; ++rg) {
            const int row = rg * 16 + m16;
            af[rg] = *(const bf16x8*)(Asrc + row * 128 + (k0 ^ ((row & 7) << 3)));
        }
#pragma unroll
        for (int cbl = 0; cbl < 2; ++cbl) {
            const int col = colb + cbl * 16 + m16;
            bf16x8 bf = *(const bf16x8*)(W + (size_t)col * 128 + k0);
#pragma unroll
            for (int rg = 0; rg < 4; ++rg)
                acc[rg][cbl] = __builtin_amdgcn_mfma_f32_16x16x32_bf16(af[rg], bf, acc[rg][cbl], 0, 0, 0);
        }
    }
    if (MIDBAR) __syncthreads();
#pragma unroll
    for (int cbl = 0; cbl < 2; ++cbl) {
        const int col = colb + cbl * 16 + m16;
        const float bv = bias[col];
#pragma unroll
        for (int rg = 0; rg < 4; ++rg)
#pragma unroll
            for (int i = 0; i < 4; ++i) {
                const int row = rg * 16 + (lane >> 4) * 4 + i;
                float v = acc[rg][cbl][i] + bv;
                if (ACT) v = lrelu(v);
                Cdst[row * 128 + (col ^ ((row & 7) << 3))] = f2b(v);
            }
    }
}

// ---- f32->bf16 weight conversion (7 tensors) ----
__global__ __launch_bounds__(256) void k_convert(
    const float* f0, const float* f1, const float* f2, const float* f3,
    const float* f4, const float* f5, const float* f6,
    short* g0, short* g1, short* g2, short* g3, short* g4, short* g5, short* g6)
{
    const float* s; short* d; int n;
    switch (blockIdx.y) {
        case 0: s = f0; d = g0; n = 655360; break;
        case 1: s = f1; d = g1; n = 327680; break;
        case 2: s = f2; d = g2; n = 327680; break;
        case 3: s = f3; d = g3; n = 327680; break;
        case 4: s = f4; d = g4; n = 131072; break;
        case 5: s = f5; d = g5; n = 131072; break;
        default: s = f6; d = g6; n = 131072; break;
    }
    int i = (blockIdx.x * 256 + threadIdx.x) * 4;
    if (i >= n) return;
    float4 v = *(const float4*)(s + i);
    s16x4 p; p.x = f2b(v.x); p.y = f2b(v.y); p.z = f2b(v.z); p.w = f2b(v.w);
    *(s16x4*)(d + i) = p;
}

// ---- K1: target chain. Block = (16 targets, s); 4 waves = 4 heads, shared A. ----
__global__ __launch_bounds__(256) void k_target(
    const float* __restrict__ x, const int* __restrict__ tgt,
    const short* __restrict__ wb_fc, const float* __restrict__ fc_b,
    const short* __restrict__ wb_q,  const float* __restrict__ q_b,
    const short* __restrict__ wb_a2, const float* __restrict__ a2_b,
    const short* __restrict__ wb_aW,
    short* __restrict__ x_shb, short* __restrict__ wh2b)
{
    const int t = threadIdx.x, lane = t & 63, w = t >> 6;
    const int bt = blockIdx.x, s = blockIdx.y;
    const int km = (s < 2) ? 0 : 1;
    const int b0 = bt * 16;
    const int sh = s * HN_ + w, kh = km * HN_ + w;   // wave w = head w

    __shared__ __align__(16) short A[16 * 256];      // 8 KB shared across heads
    __shared__ __align__(16) short BUF[4 * 2048];    // 4 KB per wave: Y->Q->H2
    short* buf0 = BUF + w * 2048;

    // gather 16 target rows (f32 -> bf16, swizzled); 16 threads per row
    {
        const int row = t >> 4, q4 = t & 15;
        const int g = tgt[b0 + row];
        const float* xr = x + (size_t)g * IN_ + q4 * 16;
        short* arow = A + row * 256;
        const int key = (row & 7) << 3;
#pragma unroll
        for (int j = 0; j < 4; ++j) {
            float4 u = *(const float4*)(xr + j * 4);
            const int c = q4 * 16 + j * 4;
            s16x4 p; p.x = f2b(u.x); p.y = f2b(u.y); p.z = f2b(u.z); p.w = f2b(u.w);
            *(s16x4*)(arow + (c ^ key)) = p;
        }
    }
    __syncthreads();

    gemm_ldsA<256, 1, true, true>(A, wb_fc + (size_t)sh * 32768, fc_b + sh * H_,
                                  buf0, x_shb + ((size_t)sh * B_ + b0) * H_, lane);
    gemm_ldsA<128, 0, true, false>(buf0, wb_q + (size_t)sh * 16384, q_b + sh * H_,
                                   buf0, nullptr, lane);
    gemm_ldsA<128, 1, true, false>(buf0, wb_a2 + (size_t)kh * 16384, a2_b + kh * H_,
                                   buf0, nullptr, lane);
    gemm_ldsA<128, 0, false, true>(buf0, wb_aW + (size_t)kh * 16384, nullptr,
                                   nullptr, wh2b + ((size_t)sh * B_ + b0) * H_, lane);
}

// ---- K2: fused neighbor pipeline. Block = (64 rows = 4 b's, s); loop h in-block. ----
__global__ __launch_bounds__(256) void k_fused(
    const float* __restrict__ x, const int* __restrict__ nbr,
    const short* __restrict__ wb_fc, const float* __restrict__ fc_b,
    const short* __restrict__ wb_k,  const float* __restrict__ k_b,
    const short* __restrict__ wb_v,  const float* __restrict__ v_b,
    const short* __restrict__ wb_a1, const float* __restrict__ a1_b,
    const short* __restrict__ x_shb, const short* __restrict__ wh2b,
    float* __restrict__ out_sbd)
{
    const int t = threadIdx.x, lane = t & 63, w = t >> 6;
    const int bt = blockIdx.x, s = blockIdx.y;
    const int km = (s < 2) ? 0 : 1;
    const int r0 = bt * 64;           // global row base (row = b*16+m)
    const int b0 = bt * 4;            // 4 targets per block

    __shared__ __align__(16) short A[64 * 256];    // 32 KB gathered neighbors
    __shared__ __align__(16) short Yt[64 * 128];   // 16 KB
    __shared__ __align__(16) short KH[64 * 128];   // 16 KB (Kh, then H1)
    __shared__ __align__(16) short VH[64 * 128];   // 16 KB

    // gather 64 neighbor rows; 4 threads per row
    {
        const int row = t >> 2, q4 = t & 3;
        const int g = nbr[(size_t)s * (B_ * M_) + r0 + row];
        const float* xr = x + (size_t)g * IN_ + q4 * 64;
        short* arow = A + row * 256;
        const int key = (row & 7) << 3;
#pragma unroll
        for (int j = 0; j < 8; ++j) {
            float4 u  = *(const float4*)(xr + j * 8);
            float4 v2 = *(const float4*)(xr + j * 8 + 4);
            const int c = q4 * 64 + j * 8;
            s16x4 p0; p0.x = f2b(u.x);  p0.y = f2b(u.y);  p0.z = f2b(u.z);  p0.w = f2b(u.w);
            s16x4 p1; p1.x = f2b(v2.x); p1.y = f2b(v2.y); p1.z = f2b(v2.z); p1.w = f2b(v2.w);
            *(s16x4*)(arow + (c ^ key)) = p0;
            *(s16x4*)(arow + (c ^ key) + 4) = p1;
        }
    }
    __syncthreads();

    const int colb = w * 32;          // this wave's output columns

    for (int h = 0; h < HN_; ++h) {
        const int sh = s * HN_ + h, kh = km * HN_ + h;

        // G1: Y = lrelu(fc(A))
        tile_gemm256<1>(A, wb_fc + (size_t)sh * 32768, fc_b + sh * H_, Yt, lane, colb);
        __syncthreads();
        // G2: Kh = k(Y); G3: Vh = v(Y)
        tile_gemm128<0, false>(Yt, wb_k + (size_t)sh * 16384, k_b + sh * H_, KH, lane, colb);
        tile_gemm128<0, false>(Yt, wb_v + (size_t)sh * 16384, v_b + sh * H_, VH, lane, colb);
        __syncthreads();
        // G4: H1 = lrelu(a1(Kh)) in-place over KH (mid barrier between read & write)
        tile_gemm128<1, true>(KH, wb_a1 + (size_t)kh * 16384, a1_b + kh * H_, KH, lane, colb);
        __syncthreads();

        // scores + softmax + PV + merge. Wave w handles b = b0 + w (tile rows 16w..16w+15)
        {
            const int b = b0 + w;
            const short* wrow = wh2b + ((size_t)sh * B_ + b) * H_;
            const int mloc = lane >> 2;              // 0..15
            const int row  = w * 16 + mloc;
            const int key  = (mloc & 7) << 3;        // (w*16)&7 == 0
            float sc = 0.f;
#pragma unroll
            for (int j8 = 0; j8 < 4; ++j8) {
                const int c = (lane & 3) * 32 + j8 * 8;
                bf16x8 hv = *(const bf16x8*)(KH + row * 128 + (c ^ key));
                bf16x8 wv = *(const bf16x8*)(wrow + c);
#pragma unroll
                for (int e2 = 0; e2 < 8; ++e2) sc += b2f(hv[e2]) * b2f(wv[e2]);
            }
            sc += __shfl_xor(sc, 1);
            sc += __shfl_xor(sc, 2);
            float ev[16];
            float mx = -1e30f;
#pragma unroll
            for (int mm = 0; mm < 16; ++mm) { ev[mm] = __shfl(sc, mm * 4); mx = fmaxf(mx, ev[mm]); }
            float ssum = 0.f;
#pragma unroll
            for (int mm = 0; mm < 16; ++mm) { ev[mm] = expf(ev[mm] - mx); ssum += ev[mm]; }
            const float inv = 1.f / ssum;

            const short* xrow = x_shb + ((size_t)sh * B_ + b) * H_;
            float* orow = out_sbd + ((size_t)s * B_ + b) * D_ + h * H_;
#pragma unroll
            for (int rep = 0; rep < 2; ++rep) {
                const int d = rep * 64 + lane;
                float hacc = 0.f;
#pragma unroll
                for (int mm = 0; mm < 16; ++mm) {
                    const float vv = b2f(VH[(w * 16 + mm) * 128 + (d ^ ((mm & 7) << 3))]);
                    hacc += lrelu(vv * (ev[mm] * inv));
                }
                orow[d] = (b2f(xrow[d]) + hacc) * 0.5f;
            }
        }
        __syncthreads();   // protect KH/VH/Yt before next head overwrites
    }
}

// ---- K3: fused inner + between semantic attention (f32) ----
__global__ __launch_bounds__(256) void k_semantic(
    const float* __restrict__ out_sbd,
    const float* __restrict__ ip1w, const float* __restrict__ ip1b,
    const float* __restrict__ ip2w,
    const float* __restrict__ bp1w, const float* __restrict__ bp1b,
    const float* __restrict__ bp2w,
    float* __restrict__ out)
{
    const int b = blockIdx.x, t = threadIdx.x;
    __shared__ float zs[S_ * D_];
    __shared__ float mps[2 * D_];
    __shared__ float red[128];
    __shared__ float svals[3];
    __shared__ float beta_s[3];

    for (int idx = t; idx < S_ * D_ / 4; idx += 256) {
        int sidx = idx >> 7, c = idx & 127;
        ((float4*)zs)[idx] = ((const float4*)(out_sbd + ((size_t)sidx * B_ + b) * D_))[c];
    }
    __syncthreads();

    for (int ki = 0; ki < 2; ++ki) {
        const int s0 = (ki == 0) ? 0 : 2;
        const int P = (ki == 0) ? 2 : 3;
        for (int p = 0; p < P; ++p) {
            if (t < H_) {
                const float* wrow = ip1w + ((size_t)ki * H_ + t) * D_;
                const float* zrow = zs + (s0 + p) * D_;
                float acc = 0.f;
                for (int d = 0; d < D_; d += 4) {
                    float4 w4 = *(const float4*)(wrow + d);
                    float4 z4 = *(const float4*)(zrow + d);
                    acc += w4.x * z4.x + w4.y * z4.y + w4.z * z4.z + w4.w * z4.w;
                }
                red[t] = tanhf(acc + ip1b[ki * H_ + t]) * ip2w[ki * H_ + t];
            }
            __syncthreads();
            if (t < 64) {
                float sv = red[t] + red[t + 64];
#pragma unroll
                for (int o = 32; o; o >>= 1) sv += __shfl_down(sv, o);
                if (t == 0) svals[p] = sv;
            }
            __syncthreads();
        }
        if (t == 0) {
            float mx = svals[0];
            for (int p = 1; p < P; ++p) mx = fmaxf(mx, svals[p]);
            float sum = 0.f;
            for (int p = 0; p < P; ++p) { float e = expf(svals[p] - mx); beta_s[p] = e; sum += e; }
            for (int p = 0; p < P; ++p) beta_s[p] /= sum;
        }
        __syncthreads();
        for (int d = t; d < D_; d += 256) {
            float acc = 0.f;
            for (int p = 0; p < P; ++p) acc += beta_s[p] * zs[(s0 + p) * D_ + d];
            mps[ki * D_ + d] = acc;
        }
        __syncthreads();
    }

    for (int p = 0; p < 2; ++p) {
        if (t < H_) {
            const float* wrow = bp1w + (size_t)t * D_;
            const float* zrow = mps + p * D_;
            float acc = 0.f;
            for (int d = 0; d < D_; d += 4) {
                float4 w4 = *(const float4*)(wrow + d);
                float4 z4 = *(const float4*)(zrow + d);
                acc += w4.x * z4.x + w4.y * z4.y + w4.z * z4.z + w4.w * z4.w;
            }
            red[t] = tanhf(acc + bp1b[t]) * bp2w[t];
        }
        __syncthreads();
        if (t < 64) {
            float sv = red[t] + red[t + 64];
#pragma unroll
            for (int o = 32; o; o >>= 1) sv += __shfl_down(sv, o);
            if (t == 0) svals[p] = sv;
        }
        __syncthreads();
    }
    if (t == 0) {
        float mx = fmaxf(svals[0], svals[1]);
        float e0 = expf(svals[0] - mx), e1 = expf(svals[1] - mx);
        float inv = 1.f / (e0 + e1);
        beta_s[0] = e0 * inv; beta_s[1] = e1 * inv;
    }
    __syncthreads();
    for (int d = t; d < D_; d += 256)
        out[(size_t)b * D_ + d] = beta_s[0] * mps[d] + beta_s[1] * mps[D_ + d];
}

extern "C" void kernel_launch(void* const* d_in, const int* in_sizes, int n_in,
                              void* d_out, int out_size, void* d_ws, size_t ws_size,
                              hipStream_t stream)
{
    const float* x    = (const float*)d_in[0];
    const int*   tgt  = (const int*)d_in[1];
    const int*   nbr  = (const int*)d_in[2];
    const float* fc_w = (const float*)d_in[3];
    const float* fc_b = (const float*)d_in[4];
    const float* q_w  = (const float*)d_in[5];
    const float* q_b  = (const float*)d_in[6];
    const float* k_w  = (const float*)d_in[7];
    const float* k_b  = (const float*)d_in[8];
    const float* v_w  = (const float*)d_in[9];
    const float* v_b  = (const float*)d_in[10];
    const float* attW = (const float*)d_in[11];
    const float* a1w  = (const float*)d_in[12];
    const float* a1b  = (const float*)d_in[13];
    const float* a2w  = (const float*)d_in[14];
    const float* a2b  = (const float*)d_in[15];
    const float* ip1w = (const float*)d_in[16];
    const float* ip1b = (const float*)d_in[17];
    const float* ip2w = (const float*)d_in[18];
    const float* bp1w = (const float*)d_in[19];
    const float* bp1b = (const float*)d_in[20];
    const float* bp2w = (const float*)d_in[21];

    float* out = (float*)d_out;

    // ws layout (shorts unless noted)
    short* wb_fc = (short*)d_ws;               // 655,360  (S,HN,H,IN)
    short* wb_q  = wb_fc + 655360;             // 327,680  (S,HN,H,H)
    short* wb_k  = wb_q + 327680;
    short* wb_v  = wb_k + 327680;
    short* wb_aW = wb_v + 327680;              // 131,072  (K,HN,H,H)
    short* wb_a1 = wb_aW + 131072;
    short* wb_a2 = wb_a1 + 131072;
    short* x_shb = wb_a2 + 131072;             // 2,621,440 (S,HN,B,H)
    short* wh2b  = x_shb + 2621440;            // 2,621,440
    float* out_sbd = (float*)(wh2b + 2621440); // 2,621,440 f32 (S,B,D)

    k_convert<<<dim3(640, 7), 256, 0, stream>>>(
        fc_w, q_w, k_w, v_w, attW, a1w, a2w,
        wb_fc, wb_q, wb_k, wb_v, wb_aW, wb_a1, wb_a2);
    k_target<<<dim3(64, 5), 256, 0, stream>>>(
        x, tgt, wb_fc, fc_b, wb_q, q_b, wb_a2, a2b, wb_aW, x_shb, wh2b);
    k_fused<<<dim3(256, 5), 256, 0, stream>>>(
        x, nbr, wb_fc, fc_b, wb_k, k_b, wb_v, v_b, wb_a1, a1b, x_shb, wh2b, out_sbd);
    k_semantic<<<dim3(B_), 256, 0, stream>>>(
        out_sbd, ip1w, ip1b, ip2w, bp1w, bp1b, bp2w, out);
}